// Round 2
// baseline (24829.488 us; speedup 1.0000x reference)
//
#include <hip/hip_runtime.h>

// TopDownTreeLSTM on MI355X — fused dataflow design, fp32 I/O (bf16-quantized values).
// k_tree: 256 persistent blocks = 32 groups x 8 col-slices. Each block holds its
// 128 gate-rows of [W_ih | W_hh] (bf16, K=512) in LDS. Batches of 16 nodes:
// M=16 K=512 MFMA computes x-part (+h-part for ready parents); in-batch chains
// fixed up serially with M=1 K=256 MFMAs accumulating into R_s. Flags count to 8.

#define N_NODES 32768
#define DD 256
#define NB 2048      // ceil((N-1)/16)
#define NGROUPS 32

typedef __attribute__((ext_vector_type(8))) short short8;
typedef __attribute__((ext_vector_type(4))) float float4_;

static __device__ __forceinline__ unsigned short f2bf(float f) {
    unsigned u = __builtin_bit_cast(unsigned, f);
    unsigned r = u + 0x7FFFu + ((u >> 16) & 1u);
    return (unsigned short)(r >> 16);
}
static __device__ __forceinline__ float bf2f(unsigned short u) {
    unsigned v = ((unsigned)u) << 16;
    return __builtin_bit_cast(float, v);
}
static __device__ __forceinline__ float sigf(float x) { return 1.0f / (1.0f + __expf(-x)); }
static __device__ __forceinline__ float tanh_(float x) { return 1.0f - 2.0f / (__expf(2.0f * x) + 1.0f); }

__global__ void k_init(int* flags) {
    int g = blockIdx.x * 256 + threadIdx.x;
    if (g < N_NODES) flags[g] = 0;
}

__global__ void k_root(const float* __restrict__ X, const float* __restrict__ state,
                       const float* __restrict__ rootW, const float* __restrict__ rootb,
                       const int* __restrict__ idx,
                       unsigned short* __restrict__ Hb, float* __restrict__ C, int* __restrict__ flags) {
    const int t = threadIdx.x;
    const int row = idx[0];
    const float4_* xr = (const float4_*)(X + (size_t)row * DD);
    const float4_* wr = (const float4_*)(rootW + (size_t)t * DD);
    float acc = rootb[t];
    for (int k = 0; k < DD / 4; ++k) {
        float4_ a = xr[k], b = wr[k];
        acc += a[0] * b[0] + a[1] * b[1] + a[2] * b[2] + a[3] * b[3];
    }
    Hb[t] = f2bf(tanh_(acc));
    C[t] = state[t];
    __syncthreads();
    __threadfence();
    if (t == 0) __hip_atomic_store(&flags[0], 8, __ATOMIC_RELEASE, __HIP_MEMORY_SCOPE_AGENT);
}

__global__ __launch_bounds__(256, 1) void k_tree(
    const float* __restrict__ X, const float* __restrict__ Wih, const float* __restrict__ Whh,
    const float* __restrict__ bih, const float* __restrict__ bhh,
    const int* __restrict__ parents, const int* __restrict__ idx,
    unsigned short* __restrict__ Hb, float* __restrict__ C, int* __restrict__ flags) {

    __shared__ __align__(16) short w_s[128 * 520];   // [128 gate-rows][512 K + 8 pad] bf16
    __shared__ __align__(16) short A_s[16 * 520];    // [16 nodes][x(256) | h(256) | pad]
    __shared__ __align__(16) float R_s[16 * 132];    // gate pre-activations (block's 128 cols)
    __shared__ float bias_s[128];
    __shared__ int par_s[16], ext_s[16], idx_s[16];

    const int tid = threadIdx.x;
    const int j = blockIdx.x & 7, grp = blockIdx.x >> 3;
    const int w = tid >> 6, l = tid & 63;
    const int lanelo = l & 15, quad = l >> 4;

    // Stage weight slice as bf16: local row r -> global gate-row G=(r>>5)*256 + j*32 + (r&31)
    for (int e = tid; e < 128 * 64; e += 256) {
        int r = e >> 6, c4 = (e & 63) * 4;
        int G = ((r >> 5) * 256) + j * 32 + (r & 31);
        float4_ a = *(const float4_*)(Wih + (size_t)G * DD + c4);
        float4_ b = *(const float4_*)(Whh + (size_t)G * DD + c4);
        unsigned short* pa = (unsigned short*)&w_s[r * 520 + c4];
        unsigned short* pb = (unsigned short*)&w_s[r * 520 + 256 + c4];
        pa[0] = f2bf(a[0]); pa[1] = f2bf(a[1]); pa[2] = f2bf(a[2]); pa[3] = f2bf(a[3]);
        pb[0] = f2bf(b[0]); pb[1] = f2bf(b[1]); pb[2] = f2bf(b[2]); pb[3] = f2bf(b[3]);
    }
    if (tid < 128) {
        int G = ((tid >> 5) * 256) + j * 32 + (tid & 31);
        bias_s[tid] = bih[G] + bhh[G];
    }
    __syncthreads();

    for (int bi = grp; bi < NB; bi += NGROUPS) {
        const int n0 = 1 + bi * 16;
        const int count = min(16, N_NODES - n0);

        // step 1: parents + classify + idx
        if (tid < 16) {
            if (tid < count) {
                int p = parents[n0 + tid];
                par_s[tid] = p;
                ext_s[tid] = (p < n0) ? 1 : 0;
                idx_s[tid] = idx[n0 + tid];
            } else { par_s[tid] = 0; ext_s[tid] = 0; idx_s[tid] = 0; }
        }
        __syncthreads();

        // step 2: stage X rows (x-half of A), bf16
        for (int e = tid; e < 16 * 64; e += 256) {
            int m = e >> 6, c4 = (e & 63) * 4;
            unsigned short* pa = (unsigned short*)&A_s[m * 520 + c4];
            if (m < count) {
                float4_ a = *(const float4_*)(X + (size_t)idx_s[m] * DD + c4);
                pa[0] = f2bf(a[0]); pa[1] = f2bf(a[1]); pa[2] = f2bf(a[2]); pa[3] = f2bf(a[3]);
            } else {
                pa[0] = 0; pa[1] = 0; pa[2] = 0; pa[3] = 0;
            }
        }

        // step 3: wait for external parents, then gather their H (h-half); zeros otherwise
        if (tid < count && ext_s[tid]) {
            const int p = par_s[tid];
            while (__hip_atomic_load(&flags[p], __ATOMIC_RELAXED, __HIP_MEMORY_SCOPE_AGENT) < 8)
                __builtin_amdgcn_s_sleep(2);
        }
        __syncthreads();
        __threadfence();   // acquire: invalidate caches before reading parents' H
        for (int e = tid; e < 16 * 128; e += 256) {
            int m = e >> 7, cu = e & 127;
            unsigned v = 0;
            if (ext_s[m]) v = ((const unsigned*)Hb)[(size_t)par_s[m] * 128 + cu];
            *(unsigned*)&A_s[m * 520 + 256 + cu * 2] = v;
        }
        __syncthreads();

        // step 4: batched M=16 K=512 MFMA -> R_s (x-part [+ h-part for ext rows])
        {
            short8 af[16];
            for (int ks = 0; ks < 16; ++ks)
                af[ks] = *(const short8*)&A_s[lanelo * 520 + ks * 32 + quad * 8];
            for (int ti = 0; ti < 2; ++ti) {
                int ntl = w * 2 + ti;
                float4_ acc = (float4_){0.f, 0.f, 0.f, 0.f};
                for (int ks = 0; ks < 16; ++ks) {
                    short8 bfrag = *(const short8*)&w_s[(ntl * 16 + lanelo) * 520 + ks * 32 + quad * 8];
                    acc = __builtin_amdgcn_mfma_f32_16x16x32_bf16(af[ks], bfrag, acc, 0, 0, 0);
                }
                for (int r = 0; r < 4; ++r)
                    R_s[(quad * 4 + r) * 132 + ntl * 16 + lanelo] = acc[r];
            }
        }
        __syncthreads();

        // step 5a: elementwise for external-parent nodes
        for (int pass = 0; pass < 2; ++pass) {
            int m = (tid >> 5) + pass * 8;
            int c = tid & 31;
            if (m < count && ext_s[m]) {
                int node = n0 + m, p = par_s[m];
                int col = j * 32 + c;
                float ig = R_s[m * 132 +       c] + bias_s[      c];
                float fg = R_s[m * 132 +  32 + c] + bias_s[ 32 + c];
                float gg = R_s[m * 132 +  64 + c] + bias_s[ 64 + c];
                float og = R_s[m * 132 +  96 + c] + bias_s[ 96 + c];
                float cp = C[(size_t)p * DD + col];
                float cn = sigf(fg) * cp + sigf(ig) * tanh_(gg);
                C[(size_t)node * DD + col] = cn;
                Hb[(size_t)node * DD + col] = f2bf(sigf(og) * tanh_(cn));
            }
        }
        __syncthreads();
        __threadfence();   // release: drain/writeback before publishing
        if (tid < count && ext_s[tid]) atomicAdd(&flags[n0 + tid], 1);

        // step 5b: serial fixups for in-batch-parent (chain) nodes
        for (int m = 0; m < count; ++m) {
            if (ext_s[m]) continue;
            const int node = n0 + m, p = par_s[m];
            if (tid == 0) {
                while (__hip_atomic_load(&flags[p], __ATOMIC_RELAXED, __HIP_MEMORY_SCOPE_AGENT) < 8)
                    __builtin_amdgcn_s_sleep(2);
            }
            __syncthreads();
            __threadfence();  // acquire
            if (tid < 128)
                *(unsigned*)&A_s[m * 520 + 256 + tid * 2] = ((const unsigned*)Hb)[(size_t)p * 128 + tid];
            __syncthreads();
            {   // M=1 recurrent MFMA (K=256, h-half only); accumulate into R_s row m
                short8 af[8];
                for (int ks = 0; ks < 8; ++ks)
                    af[ks] = *(const short8*)&A_s[lanelo * 520 + 256 + ks * 32 + quad * 8];
                for (int ti = 0; ti < 2; ++ti) {
                    int ntl = w * 2 + ti;
                    float4_ acc = (float4_){0.f, 0.f, 0.f, 0.f};
                    for (int ks = 0; ks < 8; ++ks) {
                        short8 bfrag = *(const short8*)&w_s[(ntl * 16 + lanelo) * 520 + 256 + ks * 32 + quad * 8];
                        acc = __builtin_amdgcn_mfma_f32_16x16x32_bf16(af[ks], bfrag, acc, 0, 0, 0);
                    }
                    if (quad == (m >> 2))
                        R_s[m * 132 + ntl * 16 + lanelo] += acc[m & 3];
                }
            }
            __syncthreads();
            if (tid < 32) {
                int c = tid, col = j * 32 + c;
                float ig = R_s[m * 132 +       c] + bias_s[      c];
                float fg = R_s[m * 132 +  32 + c] + bias_s[ 32 + c];
                float gg = R_s[m * 132 +  64 + c] + bias_s[ 64 + c];
                float og = R_s[m * 132 +  96 + c] + bias_s[ 96 + c];
                float cp = C[(size_t)p * DD + col];
                float cn = sigf(fg) * cp + sigf(ig) * tanh_(gg);
                C[(size_t)node * DD + col] = cn;
                Hb[(size_t)node * DD + col] = f2bf(sigf(og) * tanh_(cn));
            }
            __syncthreads();
            __threadfence();  // release
            if (tid == 0) atomicAdd(&flags[node], 1);
        }
        __syncthreads();  // protect shared tiles before next batch
    }
}

__global__ void k_out(const unsigned short* __restrict__ Hb, const float* __restrict__ C,
                      const int* __restrict__ idx, float* __restrict__ out) {
    const int b = blockIdx.x, t = threadIdx.x;
    if (b < N_NODES) {
        int drow = idx[b];
        out[512 + (size_t)drow * DD + t] = bf2f(Hb[(size_t)b * DD + t]);
    } else {
        out[t] = C[t];
        out[DD + t] = bf2f(Hb[t]);
    }
}

extern "C" void kernel_launch(void* const* d_in, const int* in_sizes, int n_in,
                              void* d_out, int out_size, void* d_ws, size_t ws_size,
                              hipStream_t stream) {
    const float* X     = (const float*)d_in[0];
    const float* state = (const float*)d_in[1];
    const float* rootW = (const float*)d_in[2];
    const float* rootb = (const float*)d_in[3];
    const float* Wih   = (const float*)d_in[4];
    const float* Whh   = (const float*)d_in[5];
    const float* bih   = (const float*)d_in[6];
    const float* bhh   = (const float*)d_in[7];
    const int* parents = (const int*)d_in[8];
    const int* idx     = (const int*)d_in[9];

    float* C            = (float*)d_ws;                               // 32 MiB
    unsigned short* Hb  = (unsigned short*)(C + (size_t)N_NODES * DD); // 16 MiB
    int* flags          = (int*)(Hb + (size_t)N_NODES * DD);           // 128 KiB
    float* out          = (float*)d_out;

    k_init<<<dim3(128), dim3(256), 0, stream>>>(flags);
    k_root<<<dim3(1), dim3(256), 0, stream>>>(X, state, rootW, rootb, idx, Hb, C, flags);
    k_tree<<<dim3(256), dim3(256), 0, stream>>>(X, Wih, Whh, bih, bhh, parents, idx, Hb, C, flags);
    k_out<<<dim3(N_NODES + 1), dim3(256), 0, stream>>>(Hb, C, idx, out);
}

// Round 3
// 6021.431 us; speedup vs baseline: 4.1235x; 4.1235x over previous
//
#include <hip/hip_runtime.h>

// TopDownTreeLSTM on MI355X — LEVEL-SCHEDULED dataflow (round 3).
// Setup: depth[] by pointer doubling (15 steps), counting-sort nodes by depth.
// k_tree2: 256 persistent blocks = 32 groups x 8 col-slices; [W_ih|W_hh] bf16
// slice in LDS. Per level d: tiles of 16 nodes -> M=16 K=512 MFMA (parents all
// at level d-1). One done[d] counter per level, target tiles*8.

#define NN 32768
#define DD 256

typedef __attribute__((ext_vector_type(8))) short short8;
typedef __attribute__((ext_vector_type(4))) float float4_;

static __device__ __forceinline__ unsigned short f2bf(float f) {
    unsigned u = __builtin_bit_cast(unsigned, f);
    unsigned r = u + 0x7FFFu + ((u >> 16) & 1u);
    return (unsigned short)(r >> 16);
}
static __device__ __forceinline__ float bf2f(unsigned short u) {
    unsigned v = ((unsigned)u) << 16;
    return __builtin_bit_cast(float, v);
}
static __device__ __forceinline__ float sigf(float x) { return 1.0f / (1.0f + __expf(-x)); }
static __device__ __forceinline__ float tanh_(float x) { return 1.0f - 2.0f / (__expf(2.0f * x) + 1.0f); }

__global__ void k_init(int* cnt, int* cur, int* done, int* maxd) {
    int g = blockIdx.x * 256 + threadIdx.x;
    if (g < NN + 2) { cnt[g] = 0; cur[g] = 0; done[g] = 0; }
    if (g == 0) maxd[0] = 0;
}

__global__ void k_root(const float* __restrict__ X, const float* __restrict__ state,
                       const float* __restrict__ rootW, const float* __restrict__ rootb,
                       const int* __restrict__ idx,
                       unsigned short* __restrict__ Hb, float* __restrict__ C, int* __restrict__ done) {
    const int t = threadIdx.x;
    const int row = idx[0];
    const float4_* xr = (const float4_*)(X + (size_t)row * DD);
    const float4_* wr = (const float4_*)(rootW + (size_t)t * DD);
    float acc = rootb[t];
    for (int k = 0; k < DD / 4; ++k) {
        float4_ a = xr[k], b = wr[k];
        acc += a[0] * b[0] + a[1] * b[1] + a[2] * b[2] + a[3] * b[3];
    }
    Hb[t] = f2bf(tanh_(acc));
    C[t] = state[t];
    __syncthreads();
    __threadfence();
    if (t == 0) __hip_atomic_store(&done[0], 8, __ATOMIC_RELEASE, __HIP_MEMORY_SCOPE_AGENT);
}

__global__ void k_dep_init(const int* __restrict__ parents, int* dep, int* jmp) {
    int i = blockIdx.x * 256 + threadIdx.x;
    if (i >= NN) return;
    dep[i] = (i == 0) ? 0 : 1;
    jmp[i] = (i == 0) ? 0 : parents[i];
}

__global__ void k_dep_step(const int* __restrict__ depA, const int* __restrict__ jmpA,
                           int* __restrict__ depB, int* __restrict__ jmpB) {
    int i = blockIdx.x * 256 + threadIdx.x;
    if (i >= NN) return;
    int j = jmpA[i];
    depB[i] = depA[i] + depA[j];
    jmpB[i] = jmpA[j];
}

__global__ void k_hist(const int* __restrict__ dep, int* cnt, int* maxd) {
    int i = blockIdx.x * 256 + threadIdx.x;
    if (i >= NN) return;
    int d = dep[i];
    atomicAdd(&cnt[d], 1);
    atomicMax(&maxd[0], d);
}

__global__ void k_scan(const int* __restrict__ cnt, int* __restrict__ off) {
    __shared__ int sums[256];
    const int tid = threadIdx.x;
    const int base = tid * 128;
    int s = 0;
    for (int k = 0; k < 128; ++k) s += cnt[base + k];
    sums[tid] = s;
    __syncthreads();
    if (tid == 0) {
        int run = 0;
        for (int t = 0; t < 256; ++t) { int tmp = sums[t]; sums[t] = run; run += tmp; }
    }
    __syncthreads();
    int run = sums[tid];
    for (int k = 0; k < 128; ++k) { off[base + k] = run; run += cnt[base + k]; }
    if (tid == 255) off[NN] = run;
}

__global__ void k_scatter(const int* __restrict__ dep, const int* __restrict__ off,
                          int* cur, int* __restrict__ lev) {
    int i = blockIdx.x * 256 + threadIdx.x;
    if (i >= NN) return;
    int d = dep[i];
    int pos = off[d] + atomicAdd(&cur[d], 1);
    lev[pos] = i;
}

__global__ __launch_bounds__(256, 1) void k_tree2(
    const float* __restrict__ X, const float* __restrict__ Wih, const float* __restrict__ Whh,
    const float* __restrict__ bih, const float* __restrict__ bhh,
    const int* __restrict__ parents, const int* __restrict__ idx,
    const int* __restrict__ off, const int* __restrict__ lev, const int* __restrict__ maxd_g,
    unsigned short* __restrict__ Hb, float* __restrict__ C, int* __restrict__ done) {

    __shared__ __align__(16) short w_s[128 * 520];   // [128 gate-rows][512 K + 8 pad] bf16
    __shared__ __align__(16) short A_s[16 * 520];    // [16 nodes][x(256) | h(256) | pad]
    __shared__ __align__(16) float R_s[16 * 132];
    __shared__ float bias_s[128];
    __shared__ int nd_s[16], par_s[16], idx_s[16];

    const int tid = threadIdx.x;
    const int j = blockIdx.x & 7, grp = blockIdx.x >> 3;
    const int w = tid >> 6, l = tid & 63;
    const int lanelo = l & 15, quad = l >> 4;

    // Stage weight slice bf16: local row r -> global gate-row G=(r>>5)*256 + j*32 + (r&31)
    for (int e = tid; e < 128 * 64; e += 256) {
        int r = e >> 6, c4 = (e & 63) * 4;
        int G = ((r >> 5) * 256) + j * 32 + (r & 31);
        float4_ a = *(const float4_*)(Wih + (size_t)G * DD + c4);
        float4_ b = *(const float4_*)(Whh + (size_t)G * DD + c4);
        unsigned short* pa = (unsigned short*)&w_s[r * 520 + c4];
        unsigned short* pb = (unsigned short*)&w_s[r * 520 + 256 + c4];
        pa[0] = f2bf(a[0]); pa[1] = f2bf(a[1]); pa[2] = f2bf(a[2]); pa[3] = f2bf(a[3]);
        pb[0] = f2bf(b[0]); pb[1] = f2bf(b[1]); pb[2] = f2bf(b[2]); pb[3] = f2bf(b[3]);
    }
    if (tid < 128) {
        int G = ((tid >> 5) * 256) + j * 32 + (tid & 31);
        bias_s[tid] = bih[G] + bhh[G];
    }
    __syncthreads();

    const int maxd = maxd_g[0];
    int prev_lo = off[0];
    int lo = off[1];
    for (int d = 1; d <= maxd; ++d) {
        const int hi = off[d + 1];
        const int width = hi - lo;
        const int tiles = (width + 15) >> 4;
        if (grp < tiles) {
            const int target = ((lo - prev_lo + 15) >> 4) * 8;
            if (tid == 0) {
                while (__hip_atomic_load(&done[d - 1], __ATOMIC_RELAXED, __HIP_MEMORY_SCOPE_AGENT) < target)
                    __builtin_amdgcn_s_sleep(2);
            }
            __syncthreads();
            __threadfence();  // acquire

            for (int t = grp; t < tiles; t += 32) {
                const int base = lo + t * 16;
                const int count = min(16, hi - base);
                if (tid < 16) {
                    if (tid < count) {
                        int node = lev[base + tid];
                        nd_s[tid] = node;
                        par_s[tid] = parents[node];
                        idx_s[tid] = idx[node];
                    } else { nd_s[tid] = -1; par_s[tid] = 0; idx_s[tid] = 0; }
                }
                __syncthreads();

                // stage x-half (fp32 -> bf16)
                for (int e = tid; e < 16 * 64; e += 256) {
                    int m = e >> 6, c4 = (e & 63) * 4;
                    unsigned short* pa = (unsigned short*)&A_s[m * 520 + c4];
                    if (nd_s[m] >= 0) {
                        float4_ a = *(const float4_*)(X + (size_t)idx_s[m] * DD + c4);
                        pa[0] = f2bf(a[0]); pa[1] = f2bf(a[1]); pa[2] = f2bf(a[2]); pa[3] = f2bf(a[3]);
                    } else { pa[0] = 0; pa[1] = 0; pa[2] = 0; pa[3] = 0; }
                }
                // stage h-half (parent H, bf16 pairs)
                for (int e = tid; e < 16 * 128; e += 256) {
                    int m = e >> 7, cu = e & 127;
                    unsigned v = 0;
                    if (nd_s[m] >= 0) v = ((const unsigned*)Hb)[(size_t)par_s[m] * 128 + cu];
                    *(unsigned*)&A_s[m * 520 + 256 + cu * 2] = v;
                }
                __syncthreads();

                // M=16 K=512 MFMA -> R_s
                {
                    short8 af[16];
                    for (int ks = 0; ks < 16; ++ks)
                        af[ks] = *(const short8*)&A_s[lanelo * 520 + ks * 32 + quad * 8];
                    for (int ti = 0; ti < 2; ++ti) {
                        int ntl = w * 2 + ti;
                        float4_ acc = (float4_){0.f, 0.f, 0.f, 0.f};
                        for (int ks = 0; ks < 16; ++ks) {
                            short8 bfrag = *(const short8*)&w_s[(ntl * 16 + lanelo) * 520 + ks * 32 + quad * 8];
                            acc = __builtin_amdgcn_mfma_f32_16x16x32_bf16(af[ks], bfrag, acc, 0, 0, 0);
                        }
                        for (int r = 0; r < 4; ++r)
                            R_s[(quad * 4 + r) * 132 + ntl * 16 + lanelo] = acc[r];
                    }
                }
                __syncthreads();

                // elementwise LSTM for the block's 32 columns
                for (int pass = 0; pass < 2; ++pass) {
                    int m = (tid >> 5) + pass * 8;
                    int c = tid & 31;
                    if (nd_s[m] >= 0) {
                        int node = nd_s[m], p = par_s[m];
                        int col = j * 32 + c;
                        float ig = R_s[m * 132 +       c] + bias_s[      c];
                        float fg = R_s[m * 132 +  32 + c] + bias_s[ 32 + c];
                        float gg = R_s[m * 132 +  64 + c] + bias_s[ 64 + c];
                        float og = R_s[m * 132 +  96 + c] + bias_s[ 96 + c];
                        float cp = C[(size_t)p * DD + col];
                        float cn = sigf(fg) * cp + sigf(ig) * tanh_(gg);
                        C[(size_t)node * DD + col] = cn;
                        Hb[(size_t)node * DD + col] = f2bf(sigf(og) * tanh_(cn));
                    }
                }
                __syncthreads();
                __threadfence();  // release
                if (tid == 0) atomicAdd(&done[d], 1);
            }
        }
        prev_lo = lo;
        lo = hi;
    }
}

__global__ void k_out(const unsigned short* __restrict__ Hb, const float* __restrict__ C,
                      const int* __restrict__ idx, float* __restrict__ out) {
    const int b = blockIdx.x, t = threadIdx.x;
    if (b < NN) {
        int drow = idx[b];
        out[512 + (size_t)drow * DD + t] = bf2f(Hb[(size_t)b * DD + t]);
    } else {
        out[t] = C[t];
        out[DD + t] = bf2f(Hb[t]);
    }
}

extern "C" void kernel_launch(void* const* d_in, const int* in_sizes, int n_in,
                              void* d_out, int out_size, void* d_ws, size_t ws_size,
                              hipStream_t stream) {
    const float* X     = (const float*)d_in[0];
    const float* state = (const float*)d_in[1];
    const float* rootW = (const float*)d_in[2];
    const float* rootb = (const float*)d_in[3];
    const float* Wih   = (const float*)d_in[4];
    const float* Whh   = (const float*)d_in[5];
    const float* bih   = (const float*)d_in[6];
    const float* bhh   = (const float*)d_in[7];
    const int* parents = (const int*)d_in[8];
    const int* idx     = (const int*)d_in[9];

    float* C           = (float*)d_ws;                                  // 32 MiB
    unsigned short* Hb = (unsigned short*)(C + (size_t)NN * DD);        // 16 MiB
    int* ip            = (int*)(Hb + (size_t)NN * DD);
    int* depA = ip;            ip += NN;
    int* jmpA = ip;            ip += NN;
    int* depB = ip;            ip += NN;
    int* jmpB = ip;            ip += NN;
    int* cnt  = ip;            ip += NN + 2;
    int* off  = ip;            ip += NN + 2;
    int* cur  = ip;            ip += NN + 2;
    int* lev  = ip;            ip += NN;
    int* done = ip;            ip += NN + 2;
    int* maxd = ip;            ip += 4;
    float* out = (float*)d_out;

    k_init<<<dim3((NN + 2 + 255) / 256), dim3(256), 0, stream>>>(cnt, cur, done, maxd);
    k_root<<<dim3(1), dim3(256), 0, stream>>>(X, state, rootW, rootb, idx, Hb, C, done);

    k_dep_init<<<dim3(128), dim3(256), 0, stream>>>(parents, depA, jmpA);
    int* dA = depA; int* jA = jmpA; int* dB = depB; int* jB = jmpB;
    for (int it = 0; it < 15; ++it) {
        k_dep_step<<<dim3(128), dim3(256), 0, stream>>>(dA, jA, dB, jB);
        int* t;
        t = dA; dA = dB; dB = t;
        t = jA; jA = jB; jB = t;
    }
    // final depth in dA
    k_hist<<<dim3(128), dim3(256), 0, stream>>>(dA, cnt, maxd);
    k_scan<<<dim3(1), dim3(256), 0, stream>>>(cnt, off);
    k_scatter<<<dim3(128), dim3(256), 0, stream>>>(dA, off, cur, lev);

    k_tree2<<<dim3(256), dim3(256), 0, stream>>>(X, Wih, Whh, bih, bhh, parents, idx,
                                                 off, lev, maxd, Hb, C, done);
    k_out<<<dim3(NN + 1), dim3(256), 0, stream>>>(Hb, C, idx, out);
}

// Round 5
// 1764.735 us; speedup vs baseline: 14.0698x; 3.4121x over previous
//
#include <hip/hip_runtime.h>

// TopDownTreeLSTM on MI355X — round 5: level-scheduled, LLC-coherent dataflow.
// (Round 4 design; fixed fence spelling -> __builtin_amdgcn_fence.)
// k_gx: Gpre[N,1024] = X·Wih^T + biases (bf16), throughput GEMM.
// k_tree2: 256 persistent blocks = 32 groups x 8 col-slices; W_hh slice (bf16,
// K=256) in LDS. Per level: prefetch Gpre tile BEFORE waiting on done[d-1];
// parent H/C via agent-scope relaxed atomics (coherent at LLC, no L2 flushes);
// one flag atomicAdd per block per level. Workgroup-scope fences only (waitcnt).

#define NN 32768
#define DD 256
#define GP 1024
#define DSTR 16   // done[] stride in ints (64B) to avoid line sharing

typedef __attribute__((ext_vector_type(8))) short short8;
typedef __attribute__((ext_vector_type(4))) float float4_;

static __device__ __forceinline__ unsigned short f2bf(float f) {
    unsigned u = __builtin_bit_cast(unsigned, f);
    unsigned r = u + 0x7FFFu + ((u >> 16) & 1u);
    return (unsigned short)(r >> 16);
}
static __device__ __forceinline__ float bf2f(unsigned short u) {
    unsigned v = ((unsigned)u) << 16;
    return __builtin_bit_cast(float, v);
}
static __device__ __forceinline__ float sigf(float x) { return 1.0f / (1.0f + __expf(-x)); }
static __device__ __forceinline__ float tanh_(float x) { return 1.0f - 2.0f / (__expf(2.0f * x) + 1.0f); }

__global__ void k_init(int* cnt, int* cur, int* done, int* maxd) {
    int g = blockIdx.x * 256 + threadIdx.x;
    if (g < NN + 2) { cnt[g] = 0; cur[g] = 0; }
    if (g < (NN + 2) * DSTR) done[g] = 0;
    if (g == 0) maxd[0] = 0;
}

__global__ void k_root(const float* __restrict__ X, const float* __restrict__ state,
                       const float* __restrict__ rootW, const float* __restrict__ rootb,
                       const int* __restrict__ idx,
                       unsigned short* __restrict__ Hb, float* __restrict__ C, int* __restrict__ done) {
    const int t = threadIdx.x;
    const int row = idx[0];
    const float4_* xr = (const float4_*)(X + (size_t)row * DD);
    const float4_* wr = (const float4_*)(rootW + (size_t)t * DD);
    float acc = rootb[t];
    for (int k = 0; k < DD / 4; ++k) {
        float4_ a = xr[k], b = wr[k];
        acc += a[0] * b[0] + a[1] * b[1] + a[2] * b[2] + a[3] * b[3];
    }
    Hb[t] = f2bf(tanh_(acc));
    C[t] = state[t];
    __syncthreads();
    __threadfence();
    if (t == 0) __hip_atomic_store(&done[0], 8, __ATOMIC_RELEASE, __HIP_MEMORY_SCOPE_AGENT);
}

__global__ void k_dep_init(const int* __restrict__ parents, int* dep, int* jmp) {
    int i = blockIdx.x * 256 + threadIdx.x;
    if (i >= NN) return;
    dep[i] = (i == 0) ? 0 : 1;
    jmp[i] = (i == 0) ? 0 : parents[i];
}

__global__ void k_dep_step(const int* __restrict__ depA, const int* __restrict__ jmpA,
                           int* __restrict__ depB, int* __restrict__ jmpB) {
    int i = blockIdx.x * 256 + threadIdx.x;
    if (i >= NN) return;
    int j = jmpA[i];
    depB[i] = depA[i] + depA[j];
    jmpB[i] = jmpA[j];
}

__global__ void k_hist(const int* __restrict__ dep, int* cnt, int* maxd) {
    int i = blockIdx.x * 256 + threadIdx.x;
    if (i >= NN) return;
    int d = dep[i];
    atomicAdd(&cnt[d], 1);
    atomicMax(&maxd[0], d);
}

__global__ void k_scan(const int* __restrict__ cnt, int* __restrict__ off) {
    __shared__ int sums[256];
    const int tid = threadIdx.x;
    const int base = tid * 128;
    int s = 0;
    for (int k = 0; k < 128; ++k) s += cnt[base + k];
    sums[tid] = s;
    __syncthreads();
    if (tid == 0) {
        int run = 0;
        for (int t = 0; t < 256; ++t) { int tmp = sums[t]; sums[t] = run; run += tmp; }
    }
    __syncthreads();
    int run = sums[tid];
    for (int k = 0; k < 128; ++k) { off[base + k] = run; run += cnt[base + k]; }
    if (tid == 255) off[NN] = run;
}

__global__ void k_scatter(const int* __restrict__ dep, const int* __restrict__ off,
                          int* cur, int* __restrict__ lev) {
    int i = blockIdx.x * 256 + threadIdx.x;
    if (i >= NN) return;
    int d = dep[i];
    int pos = off[d] + atomicAdd(&cur[d], 1);
    lev[pos] = i;
}

// Throughput GEMM: Gpre[n][g] = sum_k X[idx[n]][k]*Wih[g][k] + bih[g] + bhh[g], bf16 out.
__global__ __launch_bounds__(256, 1) void k_gx(
    const float* __restrict__ X, const float* __restrict__ Wih,
    const float* __restrict__ bih, const float* __restrict__ bhh,
    const int* __restrict__ idx, unsigned short* __restrict__ Gp) {
    __shared__ __align__(16) short bw_s[128 * 264];
    __shared__ float bias_s[128];
    const int tid = threadIdx.x;
    const int w = tid >> 6, l = tid & 63;
    const int lanelo = l & 15, quad = l >> 4;

    short8 a[2][8];
    #pragma unroll
    for (int ti = 0; ti < 2; ++ti) {
        int n = (blockIdx.x * 8 + w * 2 + ti) * 16 + lanelo;
        int row = idx[n];
        const float* xp = X + (size_t)row * DD + quad * 8;
        #pragma unroll
        for (int ks = 0; ks < 8; ++ks) {
            float4_ x0 = *(const float4_*)(xp + ks * 32);
            float4_ x1 = *(const float4_*)(xp + ks * 32 + 4);
            short8 s;
            s[0] = f2bf(x0[0]); s[1] = f2bf(x0[1]); s[2] = f2bf(x0[2]); s[3] = f2bf(x0[3]);
            s[4] = f2bf(x1[0]); s[5] = f2bf(x1[1]); s[6] = f2bf(x1[2]); s[7] = f2bf(x1[3]);
            a[ti][ks] = s;
        }
    }
    for (int gc = 0; gc < 8; ++gc) {
        __syncthreads();
        for (int e = tid; e < 128 * 64; e += 256) {
            int r = e >> 6, c4 = (e & 63) * 4;
            float4_ b = *(const float4_*)(Wih + (size_t)(gc * 128 + r) * DD + c4);
            unsigned short* pb = (unsigned short*)&bw_s[r * 264 + c4];
            pb[0] = f2bf(b[0]); pb[1] = f2bf(b[1]); pb[2] = f2bf(b[2]); pb[3] = f2bf(b[3]);
        }
        if (tid < 128) bias_s[tid] = bih[gc * 128 + tid] + bhh[gc * 128 + tid];
        __syncthreads();
        #pragma unroll
        for (int ntl = 0; ntl < 8; ++ntl) {
            float4_ acc0 = (float4_){0.f, 0.f, 0.f, 0.f};
            float4_ acc1 = (float4_){0.f, 0.f, 0.f, 0.f};
            #pragma unroll
            for (int ks = 0; ks < 8; ++ks) {
                short8 bf = *(const short8*)&bw_s[(ntl * 16 + lanelo) * 264 + ks * 32 + quad * 8];
                acc0 = __builtin_amdgcn_mfma_f32_16x16x32_bf16(a[0][ks], bf, acc0, 0, 0, 0);
                acc1 = __builtin_amdgcn_mfma_f32_16x16x32_bf16(a[1][ks], bf, acc1, 0, 0, 0);
            }
            float bia = bias_s[ntl * 16 + lanelo];
            int g = gc * 128 + ntl * 16 + lanelo;
            int nb0 = (blockIdx.x * 8 + w * 2) * 16 + quad * 4;
            #pragma unroll
            for (int r = 0; r < 4; ++r) {
                Gp[(size_t)(nb0 + r) * GP + g] = f2bf(acc0[r] + bia);
                Gp[(size_t)(nb0 + 16 + r) * GP + g] = f2bf(acc1[r] + bia);
            }
        }
    }
}

__global__ __launch_bounds__(256, 1) void k_tree2(
    const float* __restrict__ Whh,
    const int* __restrict__ parents,
    const int* __restrict__ off, const int* __restrict__ lev, const int* __restrict__ maxd_g,
    const unsigned short* __restrict__ Gp,
    unsigned short* __restrict__ Hb, float* __restrict__ C, int* __restrict__ done) {

    __shared__ __align__(16) short w_s[128 * 264];   // W_hh slice, bf16, K=256
    __shared__ __align__(16) short A_s[16 * 264];    // parent H rows, bf16
    __shared__ __align__(16) float G_s[16 * 128];    // Gpre tile (this block's 128 gate cols)
    __shared__ __align__(16) float R_s[16 * 132];    // recurrent gate partials
    __shared__ int nd_s[16], par_s[16];

    const int tid = threadIdx.x;
    const int j = blockIdx.x & 7, grp = blockIdx.x >> 3;
    const int w = tid >> 6, l = tid & 63;
    const int lanelo = l & 15, quad = l >> 4;

    // Stage W_hh slice: local row r -> global gate-row (r>>5)*256 + j*32 + (r&31)
    for (int e = tid; e < 128 * 64; e += 256) {
        int r = e >> 6, c4 = (e & 63) * 4;
        int G = ((r >> 5) * 256) + j * 32 + (r & 31);
        float4_ b = *(const float4_*)(Whh + (size_t)G * DD + c4);
        unsigned short* pb = (unsigned short*)&w_s[r * 264 + c4];
        pb[0] = f2bf(b[0]); pb[1] = f2bf(b[1]); pb[2] = f2bf(b[2]); pb[3] = f2bf(b[3]);
    }
    __syncthreads();

    const int maxd = maxd_g[0];
    int prev_lo = off[0], lo = off[1];
    for (int d = 1; d <= maxd; ++d) {
        const int hi = off[d + 1];
        const int tiles = (hi - lo + 15) >> 4;
        if (grp < tiles) {
            const int target = ((lo - prev_lo + 15) >> 4) << 3;
            int ndone = 0;
            for (int t = grp; t < tiles; t += 32) {
                const int base = lo + t * 16;
                if (tid < 16) {
                    int node = -1, p = 0;
                    if (base + tid < hi) { node = lev[base + tid]; p = parents[node]; }
                    nd_s[tid] = node; par_s[tid] = p;
                }
                __syncthreads();
                // Prefetch Gpre tile (no parent dependency) BEFORE the wait.
                {
                    int m = tid >> 4, q8 = (tid & 15) * 8;
                    int seg = q8 >> 5, cc = q8 & 31;
                    float4_ g01 = (float4_){0.f, 0.f, 0.f, 0.f};
                    float4_ g23 = (float4_){0.f, 0.f, 0.f, 0.f};
                    if (nd_s[m] >= 0) {
                        const unsigned short* gp =
                            Gp + (size_t)nd_s[m] * GP + seg * 256 + j * 32 + cc;
                        short8 gv = *(const short8*)gp;
                        g01[0] = bf2f(gv[0]); g01[1] = bf2f(gv[1]); g01[2] = bf2f(gv[2]); g01[3] = bf2f(gv[3]);
                        g23[0] = bf2f(gv[4]); g23[1] = bf2f(gv[5]); g23[2] = bf2f(gv[6]); g23[3] = bf2f(gv[7]);
                    }
                    *(float4_*)&G_s[m * 128 + q8] = g01;
                    *(float4_*)&G_s[m * 128 + q8 + 4] = g23;
                }
                if (t == grp) {
                    if (tid == 0) {
                        while (__hip_atomic_load(&done[(d - 1) * DSTR], __ATOMIC_RELAXED,
                                                 __HIP_MEMORY_SCOPE_AGENT) < target)
                            __builtin_amdgcn_s_sleep(1);
                    }
                    __syncthreads();
                    __builtin_amdgcn_fence(__ATOMIC_ACQUIRE, "workgroup");
                }
                // Parent C prefetch (latency hides under staging+MFMA).
                float cp0, cp1;
                {
                    int m0 = tid >> 5, c0 = tid & 31, col = j * 32 + c0;
                    cp0 = __hip_atomic_load(&C[(size_t)par_s[m0] * DD + col],
                                            __ATOMIC_RELAXED, __HIP_MEMORY_SCOPE_AGENT);
                    cp1 = __hip_atomic_load(&C[(size_t)par_s[m0 + 8] * DD + col],
                                            __ATOMIC_RELAXED, __HIP_MEMORY_SCOPE_AGENT);
                }
                // Parent H staging: 8 coherent u32 loads/thread, then LDS writes.
                {
                    const unsigned* HbU = (const unsigned*)Hb;
                    unsigned hv[8];
                    #pragma unroll
                    for (int k2 = 0; k2 < 8; ++k2) {
                        int e = tid + k2 * 256, m = e >> 7, cu = e & 127;
                        hv[k2] = (nd_s[m] >= 0)
                            ? __hip_atomic_load(&HbU[(size_t)par_s[m] * 128 + cu],
                                                __ATOMIC_RELAXED, __HIP_MEMORY_SCOPE_AGENT)
                            : 0u;
                    }
                    #pragma unroll
                    for (int k2 = 0; k2 < 8; ++k2) {
                        int e = tid + k2 * 256, m = e >> 7, cu = e & 127;
                        *(unsigned*)&A_s[m * 264 + cu * 2] = hv[k2];
                    }
                }
                __syncthreads();
                // M=16 K=256 MFMA -> R_s
                {
                    short8 af[8];
                    #pragma unroll
                    for (int ks = 0; ks < 8; ++ks)
                        af[ks] = *(const short8*)&A_s[lanelo * 264 + ks * 32 + quad * 8];
                    #pragma unroll
                    for (int ti = 0; ti < 2; ++ti) {
                        int ntl = w * 2 + ti;
                        float4_ acc = (float4_){0.f, 0.f, 0.f, 0.f};
                        #pragma unroll
                        for (int ks = 0; ks < 8; ++ks) {
                            short8 bf = *(const short8*)&w_s[(ntl * 16 + lanelo) * 264 + ks * 32 + quad * 8];
                            acc = __builtin_amdgcn_mfma_f32_16x16x32_bf16(af[ks], bf, acc, 0, 0, 0);
                        }
                        #pragma unroll
                        for (int r = 0; r < 4; ++r)
                            R_s[(quad * 4 + r) * 132 + ntl * 16 + lanelo] = acc[r];
                    }
                }
                __syncthreads();
                // Elementwise LSTM for the block's 32 cols; coherent stores.
                {
                    int m0 = tid >> 5, c = tid & 31, col = j * 32 + c;
                    #pragma unroll
                    for (int pass = 0; pass < 2; ++pass) {
                        int m = m0 + pass * 8;
                        float cp = pass ? cp1 : cp0;
                        float ig = R_s[m * 132 + c]      + G_s[m * 128 + c];
                        float fg = R_s[m * 132 + 32 + c] + G_s[m * 128 + 32 + c];
                        float gg = R_s[m * 132 + 64 + c] + G_s[m * 128 + 64 + c];
                        float og = R_s[m * 132 + 96 + c] + G_s[m * 128 + 96 + c];
                        float cn = sigf(fg) * cp + sigf(ig) * tanh_(gg);
                        float hn = sigf(og) * tanh_(cn);
                        int node = nd_s[m];
                        unsigned short hs = f2bf(hn);
                        unsigned pair = ((unsigned)hs) |
                                        (((unsigned)(unsigned short)__shfl_down((int)hs, 1)) << 16);
                        if (node >= 0) {
                            __hip_atomic_store(&C[(size_t)node * DD + col], cn,
                                               __ATOMIC_RELAXED, __HIP_MEMORY_SCOPE_AGENT);
                            if ((c & 1) == 0)
                                __hip_atomic_store(&((unsigned*)Hb)[(size_t)node * 128 + (col >> 1)],
                                                   pair, __ATOMIC_RELAXED, __HIP_MEMORY_SCOPE_AGENT);
                        }
                    }
                }
                ndone++;
                __syncthreads();
            }
            // All stores are LLC-coherent; wg-release fence = s_waitcnt only, then publish.
            __builtin_amdgcn_fence(__ATOMIC_RELEASE, "workgroup");
            if (tid == 0)
                __hip_atomic_fetch_add(&done[d * DSTR], ndone,
                                       __ATOMIC_RELAXED, __HIP_MEMORY_SCOPE_AGENT);
        }
        prev_lo = lo; lo = hi;
    }
}

__global__ void k_out(const unsigned short* __restrict__ Hb, const float* __restrict__ C,
                      const int* __restrict__ idx, float* __restrict__ out) {
    const int b = blockIdx.x, t = threadIdx.x;
    if (b < NN) {
        int drow = idx[b];
        out[512 + (size_t)drow * DD + t] = bf2f(Hb[(size_t)b * DD + t]);
    } else {
        out[t] = C[t];
        out[DD + t] = bf2f(Hb[t]);
    }
}

extern "C" void kernel_launch(void* const* d_in, const int* in_sizes, int n_in,
                              void* d_out, int out_size, void* d_ws, size_t ws_size,
                              hipStream_t stream) {
    const float* X     = (const float*)d_in[0];
    const float* state = (const float*)d_in[1];
    const float* rootW = (const float*)d_in[2];
    const float* rootb = (const float*)d_in[3];
    const float* Wih   = (const float*)d_in[4];
    const float* Whh   = (const float*)d_in[5];
    const float* bih   = (const float*)d_in[6];
    const float* bhh   = (const float*)d_in[7];
    const int* parents = (const int*)d_in[8];
    const int* idx     = (const int*)d_in[9];

    float* C           = (float*)d_ws;                                   // 32 MiB
    unsigned short* Hb = (unsigned short*)(C + (size_t)NN * DD);         // 16 MiB
    unsigned short* Gp = Hb + (size_t)NN * DD;                           // 64 MiB
    int* ip            = (int*)(Gp + (size_t)NN * GP);
    int* depA = ip;            ip += NN;
    int* jmpA = ip;            ip += NN;
    int* depB = ip;            ip += NN;
    int* jmpB = ip;            ip += NN;
    int* cnt  = ip;            ip += NN + 2;
    int* off  = ip;            ip += NN + 2;
    int* cur  = ip;            ip += NN + 2;
    int* lev  = ip;            ip += NN;
    int* done = ip;            ip += (NN + 2) * DSTR;
    int* maxd = ip;            ip += 4;
    float* out = (float*)d_out;

    k_init<<<dim3(((NN + 2) * DSTR + 255) / 256), dim3(256), 0, stream>>>(cnt, cur, done, maxd);
    k_root<<<dim3(1), dim3(256), 0, stream>>>(X, state, rootW, rootb, idx, Hb, C, done);

    k_dep_init<<<dim3(128), dim3(256), 0, stream>>>(parents, depA, jmpA);
    int* dA = depA; int* jA = jmpA; int* dB = depB; int* jB = jmpB;
    for (int it = 0; it < 15; ++it) {
        k_dep_step<<<dim3(128), dim3(256), 0, stream>>>(dA, jA, dB, jB);
        int* tp;
        tp = dA; dA = dB; dB = tp;
        tp = jA; jA = jB; jB = tp;
    }
    k_hist<<<dim3(128), dim3(256), 0, stream>>>(dA, cnt, maxd);
    k_scan<<<dim3(1), dim3(256), 0, stream>>>(cnt, off);
    k_scatter<<<dim3(128), dim3(256), 0, stream>>>(dA, off, cur, lev);

    k_gx<<<dim3(256), dim3(256), 0, stream>>>(X, Wih, bih, bhh, idx, Gp);
    k_tree2<<<dim3(256), dim3(256), 0, stream>>>(Whh, parents, off, lev, maxd, Gp, Hb, C, done);
    k_out<<<dim3(NN + 1), dim3(256), 0, stream>>>(Hb, C, idx, out);
}